// Round 1
// baseline (788.886 us; speedup 1.0000x reference)
//
#include <hip/hip_runtime.h>
#include <math.h>

// Problem constants
#define BB   2
#define SS   1024
#define HH   4096
#define NHH  32
#define NKVV 8
#define HDD  128
#define MR   2048   // B*S
#define KVD  1024   // NKV*HD
#define NQKVD 6144  // H + 2*KVD
#define SCALE_F 0.08838834764831845f  // 1/sqrt(128)

typedef __attribute__((ext_vector_type(8))) short bf16x8;
typedef __attribute__((ext_vector_type(4))) float f32x4;

#define MFMA(a, b, c) __builtin_amdgcn_mfma_f32_16x16x32_bf16((a), (b), (c), 0, 0, 0)

__device__ __forceinline__ unsigned short f2bf(float f) {
  union { float f; unsigned u; } v; v.f = f;
  return (unsigned short)((v.u + 0x7fffu + ((v.u >> 16) & 1u)) >> 16);
}

// async global->LDS, 16B per lane. LDS dest must be wave-uniform base + lane*16.
__device__ __forceinline__ void gload_lds16(const void* g, void* l) {
  __builtin_amdgcn_global_load_lds(
      (const __attribute__((address_space(1))) void*)g,
      (__attribute__((address_space(3))) void*)l, 16, 0, 0);
}

// ---------------- conversions ----------------
__global__ void cvt_f32_bf16(const float* __restrict__ in, unsigned short* __restrict__ out, int n4) {
  int i = blockIdx.x * blockDim.x + threadIdx.x;
  if (i >= n4) return;
  float4 v = ((const float4*)in)[i];
  union { unsigned short s[4]; uint2 d; } o;
  o.s[0] = f2bf(v.x); o.s[1] = f2bf(v.y); o.s[2] = f2bf(v.z); o.s[3] = f2bf(v.w);
  ((uint2*)out)[i] = o.d;
}

__global__ void cvt_i32_bf16(const int* __restrict__ in, unsigned short* __restrict__ out, int n4) {
  int i = blockIdx.x * blockDim.x + threadIdx.x;
  if (i >= n4) return;
  int4 v = ((const int4*)in)[i];
  union { unsigned short s[4]; uint2 d; } o;
  o.s[0] = f2bf((float)v.x); o.s[1] = f2bf((float)v.y);
  o.s[2] = f2bf((float)v.z); o.s[3] = f2bf((float)v.w);
  ((uint2*)out)[i] = o.d;
}

// ---------------- GEMM: C = A[M,K] * W[N,K]^T, 128x128 tile, BK=32 ----------------
// MODE 0: fused QKV epilogue (cols <4096 -> Q bf16 std; <5120 -> K bf16 std; else V bf16 TRANSPOSED)
// MODE 1: O-proj epilogue (fp32 out, scale only)
template <int MODE>
__global__ __launch_bounds__(256) void gemm128(
    const unsigned short* __restrict__ A, const unsigned short* __restrict__ W, int Kdim,
    const float* __restrict__ sQ, const float* __restrict__ bQ,
    const float* __restrict__ sK, const float* __restrict__ bK,
    const float* __restrict__ sV,
    unsigned short* __restrict__ oQ, unsigned short* __restrict__ oK,
    unsigned short* __restrict__ oVt,
    const float* __restrict__ sO, float* __restrict__ oO) {
  __shared__ unsigned short ldsA[128 * 32];
  __shared__ unsigned short ldsB[128 * 32];
  const int t = threadIdx.x;
  const int lane = t & 63;
  const int w = t >> 6;
  const int wr = w & 1, wc = w >> 1;
  const int l15 = lane & 15, quad = lane >> 4;
  const int bm = blockIdx.y, bn = blockIdx.x;

  // staging: thread t covers 8 contiguous elems; LDS layout row-major [128][32], no pad
  const int srow = t >> 2;
  const int scol = (t & 3) * 8;
  const unsigned short* gA = A + (size_t)(bm * 128 + srow) * Kdim + scol;
  const unsigned short* gW = W + (size_t)(bn * 128 + srow) * Kdim + scol;
  unsigned short* lA = ldsA + t * 8;  // byte off = t*16 = wave base + lane*16
  unsigned short* lB = ldsB + t * 8;

  f32x4 acc[4][4] = {};

  for (int k0 = 0; k0 < Kdim; k0 += 32) {
    __syncthreads();
    gload_lds16(gA + k0, lA);
    gload_lds16(gA + (size_t)64 * Kdim + k0, lA + 2048);
    gload_lds16(gW + k0, lB);
    gload_lds16(gW + (size_t)64 * Kdim + k0, lB + 2048);
    __syncthreads();
    bf16x8 af[4], bfr[4];
#pragma unroll
    for (int mi = 0; mi < 4; ++mi)
      af[mi] = *(const bf16x8*)(ldsA + (wr * 64 + mi * 16 + l15) * 32 + quad * 8);
#pragma unroll
    for (int ni = 0; ni < 4; ++ni)
      bfr[ni] = *(const bf16x8*)(ldsB + (wc * 64 + ni * 16 + l15) * 32 + quad * 8);
#pragma unroll
    for (int mi = 0; mi < 4; ++mi)
#pragma unroll
      for (int ni = 0; ni < 4; ++ni)
        acc[mi][ni] = MFMA(af[mi], bfr[ni], acc[mi][ni]);
  }

  // epilogue; C/D layout: row = quad*4 + r, col = lane&15 (m89-verified)
  const int row0 = bm * 128 + wr * 64 + quad * 4;
  const int col0 = bn * 128 + wc * 64 + l15;
#pragma unroll
  for (int mi = 0; mi < 4; ++mi) {
#pragma unroll
    for (int ni = 0; ni < 4; ++ni) {
      const int col = col0 + ni * 16;
#pragma unroll
      for (int r = 0; r < 4; ++r) {
        const int row = row0 + mi * 16 + r;
        float v = acc[mi][ni][r];
        if (MODE == 0) {
          if (col < HH) {
            v = v * sQ[col] + bQ[col];
            oQ[(size_t)row * HH + col] = f2bf(v);
          } else if (col < HH + KVD) {
            const int c = col - HH;
            v = v * sK[c] + bK[c];
            oK[(size_t)row * KVD + c] = f2bf(v);
          } else {
            const int c = col - HH - KVD;
            v = v * sV[c];
            oVt[(size_t)c * MR + row] = f2bf(v);  // transposed store for PV B-frags
          }
        } else {
          oO[(size_t)row * HH + col] = v * sO[col];
        }
      }
    }
  }
}

// ---------------- flash attention: 1 wave per (b, h, 16 q-rows), k-tiles of 32 ----------------
__global__ __launch_bounds__(64) void attn_kernel(
    const unsigned short* __restrict__ Q,   // [2048][4096]
    const unsigned short* __restrict__ K,   // [2048][1024]
    const unsigned short* __restrict__ Vt,  // [1024][2048] (channel-major)
    unsigned short* __restrict__ O) {       // [2048][4096]
  __shared__ unsigned short lds_p[16 * 32];
  const int lane = threadIdx.x;
  const int l15 = lane & 15, quad = lane >> 4;
  const int qb = blockIdx.x;  // 0..63
  const int h = blockIdx.y;   // 0..31
  const int b = blockIdx.z;   // 0..1
  const int kv = h >> 2;      // GROUPS=4
  const int q0 = qb * 16;

  // Q A-frags: A[m=l15][k=quad*8+j], 4 frags cover HD=128
  bf16x8 aq[4];
  const unsigned short* qbase = Q + (size_t)(b * SS + q0 + l15) * HH + h * HDD + quad * 8;
#pragma unroll
  for (int kk = 0; kk < 4; ++kk) aq[kk] = *(const bf16x8*)(qbase + kk * 32);

  f32x4 accO[8] = {};
  float m_run[4] = {-3.0e38f, -3.0e38f, -3.0e38f, -3.0e38f};
  float l_run[4] = {0.f, 0.f, 0.f, 0.f};

  const int nkt = qb / 2 + 1;  // causal: k0 <= q0+15
  for (int kt = 0; kt < nkt; ++kt) {
    const int k0 = kt * 32;
    // QK^T: 16x32 scores as two 16x16 C-frags
    f32x4 s0 = {}, s1 = {};
    const unsigned short* kb = K + (size_t)(b * SS + k0 + l15) * KVD + kv * HDD + quad * 8;
#pragma unroll
    for (int kk = 0; kk < 4; ++kk) {
      bf16x8 b0 = *(const bf16x8*)(kb + kk * 32);
      bf16x8 b1 = *(const bf16x8*)(kb + (size_t)16 * KVD + kk * 32);
      s0 = MFMA(aq[kk], b0, s0);
      s1 = MFMA(aq[kk], b1, s1);
    }
    // online softmax (rows live in 16-lane groups: row = q0 + quad*4 + r, col = k0 + f*16 + l15)
    float alpha[4], pw0[4], pw1[4];
#pragma unroll
    for (int r = 0; r < 4; ++r) {
      const int qrow = q0 + quad * 4 + r;
      float v0 = s0[r] * SCALE_F; if (k0 + l15 > qrow) v0 = -3.0e38f;
      float v1 = s1[r] * SCALE_F; if (k0 + 16 + l15 > qrow) v1 = -3.0e38f;
      float cm = fmaxf(v0, v1);
      cm = fmaxf(cm, __shfl_xor(cm, 1, 16));
      cm = fmaxf(cm, __shfl_xor(cm, 2, 16));
      cm = fmaxf(cm, __shfl_xor(cm, 4, 16));
      cm = fmaxf(cm, __shfl_xor(cm, 8, 16));
      const float mn = fmaxf(m_run[r], cm);
      const float al = __expf(m_run[r] - mn);
      const float p0 = __expf(v0 - mn);  // masked -> exp(-huge) == 0
      const float p1 = __expf(v1 - mn);
      float sum = p0 + p1;
      sum += __shfl_xor(sum, 1, 16);
      sum += __shfl_xor(sum, 2, 16);
      sum += __shfl_xor(sum, 4, 16);
      sum += __shfl_xor(sum, 8, 16);
      l_run[r] = l_run[r] * al + sum;
      m_run[r] = mn;
      alpha[r] = al;
      pw0[r] = p0; pw1[r] = p1;
    }
#pragma unroll
    for (int cb = 0; cb < 8; ++cb)
#pragma unroll
      for (int r = 0; r < 4; ++r) accO[cb][r] *= alpha[r];
    // P: C-layout -> LDS -> A-layout (m120-verified round trip)
    __syncthreads();
#pragma unroll
    for (int r = 0; r < 4; ++r) {
      lds_p[(quad * 4 + r) * 32 + l15] = f2bf(pw0[r]);
      lds_p[(quad * 4 + r) * 32 + 16 + l15] = f2bf(pw1[r]);
    }
    __syncthreads();
    bf16x8 ap = *(const bf16x8*)(lds_p + l15 * 32 + quad * 8);
    // PV: B[k][n] = V[s=k0+quad*8+j][hd] = Vt[hd][k0+quad*8+j] -> contiguous 16B
    const unsigned short* vb = Vt + (size_t)(kv * HDD + l15) * MR + b * SS + k0 + quad * 8;
#pragma unroll
    for (int cb = 0; cb < 8; ++cb) {
      bf16x8 bv = *(const bf16x8*)(vb + (size_t)cb * 16 * MR);
      accO[cb] = MFMA(ap, bv, accO[cb]);
    }
  }
  // epilogue: O[row][h*128 + cb*16 + col] = accO/l
  unsigned short* ob = O + (size_t)(b * SS + q0 + quad * 4) * HH + h * HDD + l15;
#pragma unroll
  for (int cb = 0; cb < 8; ++cb)
#pragma unroll
    for (int r = 0; r < 4; ++r)
      ob[(size_t)r * HH + cb * 16] = f2bf(accO[cb][r] / l_run[r]);
}

extern "C" void kernel_launch(void* const* d_in, const int* in_sizes, int n_in,
                              void* d_out, int out_size, void* d_ws, size_t ws_size,
                              hipStream_t stream) {
  const float* x = (const float*)d_in[0];
  // d_in[1] = attention_mask: exact causal, applied analytically
  const int* wq = (const int*)d_in[2];
  const float* wqs = (const float*)d_in[3];
  const float* bq = (const float*)d_in[4];
  const int* wk = (const int*)d_in[5];
  const float* wks = (const float*)d_in[6];
  const float* bk = (const float*)d_in[7];
  const int* wv = (const int*)d_in[8];
  const float* wvs = (const float*)d_in[9];
  const int* wo = (const int*)d_in[10];
  const float* wos = (const float*)d_in[11];
  float* out = (float*)d_out;
  char* ws = (char*)d_ws;

  // workspace layout (MiB offsets): total 136 MiB
  unsigned short* x_bf = (unsigned short*)(ws + (0ull << 20));     // 16 MiB  [2048][4096]
  unsigned short* wqkv_bf = (unsigned short*)(ws + (16ull << 20)); // 48 MiB  [6144][4096]
  unsigned short* wo_bf = (unsigned short*)(ws + (64ull << 20));   // 32 MiB  [4096][4096]
  unsigned short* q_bf = (unsigned short*)(ws + (96ull << 20));    // 16 MiB  [2048][4096]
  unsigned short* k_bf = (unsigned short*)(ws + (112ull << 20));   // 4 MiB   [2048][1024]
  unsigned short* v_t = (unsigned short*)(ws + (116ull << 20));    // 4 MiB   [1024][2048]
  unsigned short* a_bf = (unsigned short*)(ws + (120ull << 20));   // 16 MiB  [2048][4096]
  if (ws_size < (136ull << 20)) return;  // insufficient scratch (would show as untouched d_out)

  cvt_f32_bf16<<<8192, 256, 0, stream>>>(x, x_bf, MR * HH / 4);
  cvt_i32_bf16<<<16384, 256, 0, stream>>>(wq, wqkv_bf, HH * HH / 4);
  cvt_i32_bf16<<<4096, 256, 0, stream>>>(wk, wqkv_bf + (size_t)HH * HH, KVD * HH / 4);
  cvt_i32_bf16<<<4096, 256, 0, stream>>>(wv, wqkv_bf + (size_t)(HH + KVD) * HH, KVD * HH / 4);
  cvt_i32_bf16<<<16384, 256, 0, stream>>>(wo, wo_bf, HH * HH / 4);

  gemm128<0><<<dim3(NQKVD / 128, MR / 128), 256, 0, stream>>>(
      x_bf, wqkv_bf, HH, wqs, bq, wks, bk, wvs, q_bf, k_bf, v_t, nullptr, nullptr);
  attn_kernel<<<dim3(SS / 16, NHH, BB), 64, 0, stream>>>(q_bf, k_bf, v_t, a_bf);
  gemm128<1><<<dim3(HH / 128, MR / 128), 256, 0, stream>>>(
      a_bf, wo_bf, HH, nullptr, nullptr, nullptr, nullptr, nullptr,
      nullptr, nullptr, nullptr, wos, out);
}